// Round 13
// baseline (137.432 us; speedup 1.0000x reference)
//
#include <hip/hip_runtime.h>
#include <hip/hip_bf16.h>
#include <stdint.h>

#define C_ 400
#define TINV 10.0f
#define ALPHA_ 0.03f

typedef __bf16 bf16x8 __attribute__((ext_vector_type(8)));
typedef float f32x4 __attribute__((ext_vector_type(4)));

__device__ __forceinline__ void load16(const void* g, void* l) {
  __builtin_amdgcn_global_load_lds(
      (const __attribute__((address_space(1))) uint32_t*)g,
      (__attribute__((address_space(3))) uint32_t*)l, 16, 0, 0);
}

// ---- K0: convert features f32->bf16 (row-permuted new_r=(r%8)*512+r/8, float4
//          vectorized) + cross-entropy partials (8 rows/block) + counter resets.
__global__ __launch_bounds__(256) void k_prep(const float* __restrict__ feat,
                                              const float* __restrict__ predicts,
                                              const int* __restrict__ labels,
                                              uint16_t* __restrict__ featB,
                                              double* __restrict__ p_ce,
                                              unsigned int* __restrict__ counter) {
  __shared__ double smr[4];
  const int t = threadIdx.x, bid = blockIdx.x;
  const int lane = t & 63, w = t >> 6;
  if (bid == 0 && t == 0) { counter[0] = 0; counter[1] = 0; }

  int idx4 = bid * 256 + t;  // 131072 float4 tasks
  int nr = idx4 >> 5, d4 = idx4 & 31;
  int r = ((nr & 511) << 3) | (nr >> 9);
  float4 v = reinterpret_cast<const float4*>(feat)[r * 32 + d4];
  __hip_bfloat16 h0 = __float2bfloat16(v.x), h1 = __float2bfloat16(v.y),
                 h2 = __float2bfloat16(v.z), h3 = __float2bfloat16(v.w);
  ushort4 o;
  o.x = *(uint16_t*)&h0; o.y = *(uint16_t*)&h1;
  o.z = *(uint16_t*)&h2; o.w = *(uint16_t*)&h3;
  reinterpret_cast<ushort4*>(featB)[idx4] = o;

  double ce = 0.0;
#pragma unroll
  for (int s = 0; s < 2; ++s) {
    int row = bid * 8 + w * 2 + s;
    const float* pr = predicts + (size_t)row * C_;
    float mx = -3.0e38f;
    for (int k = lane; k < C_; k += 64) mx = fmaxf(mx, pr[k]);
#pragma unroll
    for (int o2 = 32; o2; o2 >>= 1) mx = fmaxf(mx, __shfl_xor(mx, o2));
    float sum = 0.f;
    for (int k = lane; k < C_; k += 64) sum += __expf(pr[k] - mx);
#pragma unroll
    for (int o2 = 32; o2; o2 >>= 1) sum += __shfl_xor(sum, o2);
    ce += (double)(__logf(sum) + mx - pr[labels[row]]);
  }
  if (lane == 0) smr[w] = ce;
  __syncthreads();
  if (t == 0) p_ce[bid] = smr[0] + smr[1] + smr[2] + smr[3];
}

// ---- K1: Gram sweep + fused post. 2048 blocks, 64-row x 128-col tile, 2x2
// wave grid (each wave 32 rows x 64 cols). B-tile staged ONCE into LDS via
// global_load_lds (st-swizzle byte^=((row&7)<<4) through inverse-swizzled
// source), ONE barrier, then swizzled ds_read_b128 fragments (each B frag read
// by 2 waves, halving R11's 4x redundancy). A-frags direct from L2 (one-time).
// Power sums into per-64-col-strip slots; partner/diag logic as verified.
// The last 128 blocks to finish take one slice each of the closed-form post
// (values deterministic; mapping arrival-ordered), last slice finalizes.
__global__ __launch_bounds__(256, 4) void k_sweep(
    const uint16_t* __restrict__ featB, float* __restrict__ S1h,
    float* __restrict__ S2h, float* __restrict__ P,
    const double* __restrict__ p_ce, double* __restrict__ p_nce,
    unsigned int* __restrict__ counter, float* __restrict__ out) {
  __shared__ alignas(16) uint16_t Bt[128 * 128];
  __shared__ double smr[4];
  __shared__ int sliceSh;
  const int t = threadIdx.x, bid = blockIdx.x;
  const int lane = t & 63, w = t >> 6;
  const int r0 = lane & 15, kq = lane >> 4, rq = kq << 2;
  const char* fb = (const char*)featB;
  const int rc = bid >> 5, cc = bid & 31;
  const int rb = rc << 6;          // 64 rows
  const int cbase = cc << 7;       // 128 cols
  const int wr = w >> 1, wc = w & 1;
  const int jb = cbase >> 9;       // pair-block of all this block's cols
  const int ib = rb >> 9;
  const int strip = ((cc << 1) | wc) & 7;

  // Stage B-tile: 128 col-rows x 256 B = 32 KB, 8 iterations.
#pragma unroll
  for (int it = 0; it < 8; ++it) {
    int L = it * 4096 + t * 16;
    int row = L >> 8;
    int kbs = (L & 255) ^ ((row & 7) << 4);
    load16(fb + (size_t)(cbase + row) * 256 + kbs, (char*)Bt + L);
  }
  // A fragments: 32 rows per wave, direct from L2 (one-time; overlaps staging).
  bf16x8 a[2][4];
#pragma unroll
  for (int rg = 0; rg < 2; ++rg) {
    const size_t ra = (size_t)(rb + wr * 32 + rg * 16 + r0) * 256 + kq * 16;
#pragma unroll
    for (int kk = 0; kk < 4; ++kk) a[rg][kk] = *(const bf16x8*)(fb + ra + kk * 64);
  }
  __syncthreads();  // single barrier: staging drained

  float s1[2][4], s2[2][4];
#pragma unroll
  for (int rg = 0; rg < 2; ++rg)
#pragma unroll
    for (int q = 0; q < 4; ++q) { s1[rg][q] = 0.f; s2[rg][q] = 0.f; }

#pragma unroll
  for (int n = 0; n < 4; ++n) {
    const int cl = wc * 64 + n * 16 + r0;  // local col-row in Bt
    bf16x8 bn[4];
#pragma unroll
    for (int kk = 0; kk < 4; ++kk)
      bn[kk] = *(const bf16x8*)((const char*)Bt + cl * 256 +
                                ((kk * 64 + kq * 16) ^ ((cl & 7) << 4)));
    f32x4 acc[2];
    acc[0] = (f32x4)0.0f;
    acc[1] = (f32x4)0.0f;
#pragma unroll
    for (int rg = 0; rg < 2; ++rg)
#pragma unroll
      for (int kk = 0; kk < 4; ++kk)
        acc[rg] = __builtin_amdgcn_mfma_f32_16x16x32_bf16(a[rg][kk], bn[kk],
                                                          acc[rg], 0, 0, 0);
#pragma unroll
    for (int rg = 0; rg < 2; ++rg)
#pragma unroll
      for (int q = 0; q < 4; ++q) {
        float e = __expf(acc[rg][q] * TINV);
        int grow = rb + wr * 32 + rg * 16 + rq + q;
        int gcol = cbase + wc * 64 + n * 16 + r0;
        if ((gcol & 511) == (grow & 511)) {
          P[(size_t)grow * 8 + jb] = e;  // partner (== Egg when jb==ib)
          if (jb == ib) e = 0.f;         // exclude exact diagonal col==row
        }
        s1[rg][q] += e;
        s2[rg][q] += e * e;
      }
  }

#pragma unroll
  for (int rg = 0; rg < 2; ++rg)
#pragma unroll
    for (int q = 0; q < 4; ++q) {
      float v1 = s1[rg][q], v2 = s2[rg][q];
#pragma unroll
      for (int o2 = 1; o2 <= 8; o2 <<= 1) {
        v1 += __shfl_xor(v1, o2);
        v2 += __shfl_xor(v2, o2);
      }
      if (r0 == 0) {
        int grow = rb + wr * 32 + rg * 16 + rq + q;
        size_t gi = ((size_t)grow * 8 + jb) * 8 + strip;
        S1h[gi] = v1;
        S2h[gi] = v2;
      }
    }

  // ---- Fused post: last 128 arrivals take one slice each.
  if (t == 0) {
    __threadfence();
    unsigned int old = atomicAdd(&counter[0], 1u);
    sliceSh = (old >= 1920u) ? (int)(old - 1920u) : -1;
  }
  __syncthreads();
  const int slice = sliceSh;
  if (slice < 0) return;
  if (t == 0) {
    while (atomicAdd(&counter[0], 0u) < 2048u) __builtin_amdgcn_s_sleep(8);
  }
  __syncthreads();
  __threadfence();

  const f32x4* S14 = (const f32x4*)S1h;
  const f32x4* S24 = (const f32x4*)S2h;
  double nce = 0.0;
  {
    int task = slice * 256 + t;  // 0..32767
    int g = task >> 3, j = task & 7, i = g >> 9;
    size_t bi = ((size_t)g * 8 + i) * 2;  // f32x4 units (8 floats/slot)
    f32x4 x0 = S14[bi], x1 = S14[bi + 1];
    f32x4 y0 = S24[bi], y1 = S24[bi + 1];
    float s1i = (x0[0] + x0[1] + x0[2] + x0[3]) + (x1[0] + x1[1] + x1[2] + x1[3]);
    float s2i = (y0[0] + y0[1] + y0[2] + y0[3]) + (y1[0] + y1[1] + y1[2] + y1[3]);
    float Egg = P[(size_t)g * 8 + i];
    float val;
    if (j != i) {
      size_t bj = ((size_t)g * 8 + j) * 2;
      f32x4 u0 = S14[bj], u1 = S14[bj + 1];
      f32x4 v0 = S24[bj], v1 = S24[bj + 1];
      float s1j = (u0[0] + u0[1] + u0[2] + u0[3]) + (u1[0] + u1[1] + u1[2] + u1[3]);
      float s2j = (v0[0] + v0[1] + v0[2] + v0[3]) + (v1[0] + v1[1] + v1[2] + v1[3]);
      float div = s1i + s1j;
      float inv = 1.f / div;
      float pmt = P[(size_t)g * 8 + j] * inv;
      float Ls = (s1i + s1j) + inv * (0.5f * (s2i + s2j));
      val = __logf(pmt) - __logf(1.f - pmt) - inv * Ls;
    } else {
      float div = 2.f * s1i + Egg;
      float inv = 1.f / div;
      float pmt = Egg * inv;
      float Ls = s1i + inv * (0.5f * s2i);
      val = 2.f * __logf(pmt) - 4.f * inv * Ls;
    }
    nce = (double)val;
  }
#pragma unroll
  for (int o2 = 32; o2; o2 >>= 1) nce += __shfl_xor(nce, o2);
  if (lane == 0) smr[w] = nce;
  __syncthreads();
  __shared__ int isLast;
  if (t == 0) {
    p_nce[slice] = smr[0] + smr[1] + smr[2] + smr[3];
    __threadfence();
    unsigned int old2 = atomicAdd(&counter[1], 1u);
    isLast = (old2 == 127u) ? 1 : 0;
  }
  __syncthreads();
  if (isLast) {
    __threadfence();
    double tn = (t < 128) ? p_nce[t] : 0.0;
    double tc = p_ce[t] + p_ce[t + 256];
#pragma unroll
    for (int o2 = 32; o2; o2 >>= 1) {
      tn += __shfl_xor(tn, o2);
      tc += __shfl_xor(tc, o2);
    }
    __shared__ double smn2[4], smc2[4];
    if (lane == 0) { smn2[w] = tn; smc2[w] = tc; }
    __syncthreads();
    if (t == 0) {
      double fn = smn2[0] + smn2[1] + smn2[2] + smn2[3];
      double fc = smc2[0] + smc2[1] + smc2[2] + smc2[3];
      out[0] = ALPHA_ * (-(float)(fn / 1024.0)) + (float)(fc / 4096.0);
    }
  }
}

__global__ void k_sentinel(float* out) {
  if (threadIdx.x == 0) out[0] = 12345.0f;
}

extern "C" void kernel_launch(void* const* d_in, const int* in_sizes, int n_in,
                              void* d_out, int out_size, void* d_ws, size_t ws_size,
                              hipStream_t stream) {
  const float* predicts = (const float*)d_in[0];
  const int* labels = (const int*)d_in[1];
  const float* features = (const float*)d_in[2];

  char* ws = (char*)d_ws;
  const size_t offFeatB = 0;                  // 1 MiB
  const size_t offS1 = 1048576;               // 4096*8*8*4 = 1 MiB
  const size_t offS2 = offS1 + 1048576;       // 1 MiB
  const size_t offP = offS2 + 1048576;        // 128 KiB
  const size_t offCe = offP + 131072;         // 512 doubles
  const size_t offNce = offCe + 4096;         // 128 doubles
  const size_t offCnt = offNce + 1024;        // 2 uints
  const size_t need = offCnt + 64;

  float* out = (float*)d_out;
  if (ws_size < need) {
    k_sentinel<<<1, 64, 0, stream>>>(out);
    return;
  }

  uint16_t* featB = (uint16_t*)(ws + offFeatB);
  float* S1h = (float*)(ws + offS1);
  float* S2h = (float*)(ws + offS2);
  float* P = (float*)(ws + offP);
  double* p_ce = (double*)(ws + offCe);
  double* p_nce = (double*)(ws + offNce);
  unsigned int* counter = (unsigned int*)(ws + offCnt);

  k_prep<<<512, 256, 0, stream>>>(features, predicts, labels, featB, p_ce, counter);
  k_sweep<<<2048, 256, 0, stream>>>(featB, S1h, S2h, P, p_ce, p_nce, counter, out);
}

// Round 14
// 31.174 us; speedup vs baseline: 4.4085x; 4.4085x over previous
//
#include <hip/hip_runtime.h>
#include <hip/hip_bf16.h>
#include <stdint.h>

#define C_ 400
#define TINV 10.0f
#define ALPHA_ 0.03f

typedef __bf16 bf16x8 __attribute__((ext_vector_type(8)));
typedef float f32x4 __attribute__((ext_vector_type(4)));

// ---- K1: fused convert + CE + single Gram sweep (verified R11 structure).
// 1024 blocks (= exactly 4 blocks/CU, one scheduling round), 64-row x 256-col
// tile each. B-tiles reg-staged from f32 feat (row-permuted
// new_r=(r%8)*512+r/8), converted to bf16 in-registers, written to
// double-buffered LDS with st-swizzle byte^=((row&7)<<4) on the ds_write
// address. Pipeline per iter: LOADF(t8+1) issue-early -> MFMA+exp on Bt[cur]
// -> WRITEB(cur^1) write-late -> barrier (skipped on last iter). A-fragments
// converted from f32 directly (one-time). CE: 1 row per wave on ALL blocks
// (tail-balanced), no smem/sync. Diagonal c==g excluded for own block;
// partner P extracted as verified. Power sums S1,S2 per (g, jb, half).
__global__ __launch_bounds__(256, 4) void k_sweep(
    const float* __restrict__ feat, const float* __restrict__ predicts,
    const int* __restrict__ labels, float* __restrict__ S1h,
    float* __restrict__ S2h, float* __restrict__ P,
    double* __restrict__ p_ce, unsigned int* __restrict__ counter) {
  __shared__ alignas(16) uint16_t Bt[2][64 * 128];
  const int t = threadIdx.x, bid = blockIdx.x;
  const int lane = t & 63, w = t >> 6;
  const int r0 = lane & 15, kq = lane >> 4, rq = kq << 2;
  if (bid == 0 && t == 0) counter[0] = 0;  // reset k_post's finalize counter

  const int rc = bid >> 4, ch = bid & 15;
  const int jb = ch >> 1, half = ch & 1;
  const int rb = rc << 6;
  const int cbase = (jb << 9) + (half << 8);  // global col start (256 cols)
  const int lc0 = half << 8;                  // local col offset in 512-block
  const int ib = rb >> 9, kbase = rb & 511;
  const bool own = (jb == ib);
  const f32x4* feat4 = (const f32x4*)feat;

  f32x4 gv[4][2];  // staging registers (32 VGPR)

#define LOADF(step)                                                 \
  _Pragma("unroll") for (int it = 0; it < 4; ++it) {                \
    int L = it * 4096 + t * 16;                                     \
    int row = L >> 8;                                               \
    int crow = cbase + (step) * 64 + row;                           \
    int oc = ((crow & 511) << 3) | (crow >> 9);                     \
    int f4 = oc * 32 + ((L & 255) >> 3);                            \
    gv[it][0] = feat4[f4];                                          \
    gv[it][1] = feat4[f4 + 1];                                      \
  }

#define WRITEB(buf)                                                 \
  _Pragma("unroll") for (int it = 0; it < 4; ++it) {                \
    int L = it * 4096 + t * 16;                                     \
    int row = L >> 8;                                               \
    int dst = L ^ ((row & 7) << 4);                                 \
    bf16x8 v;                                                       \
    v[0] = (__bf16)gv[it][0][0]; v[1] = (__bf16)gv[it][0][1];       \
    v[2] = (__bf16)gv[it][0][2]; v[3] = (__bf16)gv[it][0][3];       \
    v[4] = (__bf16)gv[it][1][0]; v[5] = (__bf16)gv[it][1][1];       \
    v[6] = (__bf16)gv[it][1][2]; v[7] = (__bf16)gv[it][1][3];       \
    *(bf16x8*)((char*)Bt[buf] + dst) = v;                           \
  }

  LOADF(0);  // issue tile-0 loads first

  // CE: one row per wave, all blocks (4096 rows / 1024 blocks / 4 waves).
  {
    int row = (bid << 2) + w;
    const float* pr = predicts + (size_t)row * C_;
    float mx = -3.0e38f;
    for (int k = lane; k < C_; k += 64) mx = fmaxf(mx, pr[k]);
#pragma unroll
    for (int o2 = 32; o2; o2 >>= 1) mx = fmaxf(mx, __shfl_xor(mx, o2));
    float sum = 0.f;
    for (int k = lane; k < C_; k += 64) sum += __expf(pr[k] - mx);
#pragma unroll
    for (int o2 = 32; o2; o2 >>= 1) sum += __shfl_xor(sum, o2);
    if (lane == 0) p_ce[row] = (double)(__logf(sum) + mx - pr[labels[row]]);
  }

  // A fragments: one-time, converted from f32 directly (L2-resident feat).
  bf16x8 a[4];
  {
    int g = rb + (w << 4) + r0;
    int og = ((g & 511) << 3) | (g >> 9);
#pragma unroll
    for (int kk = 0; kk < 4; ++kk) {
      f32x4 u0 = feat4[og * 32 + kk * 8 + kq * 2];
      f32x4 u1 = feat4[og * 32 + kk * 8 + kq * 2 + 1];
      bf16x8 av;
      av[0] = (__bf16)u0[0]; av[1] = (__bf16)u0[1];
      av[2] = (__bf16)u0[2]; av[3] = (__bf16)u0[3];
      av[4] = (__bf16)u1[0]; av[5] = (__bf16)u1[1];
      av[6] = (__bf16)u1[2]; av[7] = (__bf16)u1[3];
      a[kk] = av;
    }
  }
  WRITEB(0);
  __syncthreads();

  float s1[4] = {0.f, 0.f, 0.f, 0.f};
  float s2[4] = {0.f, 0.f, 0.f, 0.f};

#pragma unroll
  for (int t8 = 0; t8 < 4; ++t8) {
    const int cur = t8 & 1;
    if (t8 < 3) LOADF(t8 + 1);  // issue next tile early
    f32x4 acc[4];
#pragma unroll
    for (int n = 0; n < 4; ++n) {
      acc[n] = (f32x4)0.0f;
      int cl = n * 16 + r0;
#pragma unroll
      for (int kk = 0; kk < 4; ++kk) {
        bf16x8 bfr = *(const bf16x8*)((const char*)Bt[cur] + cl * 256 +
                                      ((kk * 64 + kq * 16) ^ ((cl & 7) << 4)));
        acc[n] = __builtin_amdgcn_mfma_f32_16x16x32_bf16(a[kk], bfr, acc[n], 0, 0, 0);
      }
    }
#pragma unroll
    for (int n = 0; n < 4; ++n)
#pragma unroll
      for (int q = 0; q < 4; ++q) {
        float e = __expf(acc[n][q] * TINV);
        int rl = (w << 4) + rq + q;
        if (lc0 + t8 * 64 + n * 16 + r0 == kbase + rl) {
          P[(size_t)(rb + rl) * 8 + jb] = e;  // partner (== Egg when own)
          if (own) e = 0.f;                   // exclude diagonal from sums
        }
        s1[q] += e;
        s2[q] += e * e;
      }
    if (t8 < 3) {
      WRITEB(cur ^ 1);  // write-late into the other buffer
      __syncthreads();  // no barrier needed after the last iteration
    }
  }

#pragma unroll
  for (int q = 0; q < 4; ++q) {
    float v1 = s1[q], v2 = s2[q];
#pragma unroll
    for (int o2 = 1; o2 <= 8; o2 <<= 1) {
      v1 += __shfl_xor(v1, o2);
      v2 += __shfl_xor(v2, o2);
    }
    if (r0 == 0) {
      size_t gi = ((size_t)(rb + (w << 4) + rq + q) * 8 + jb) * 2 + half;
      S1h[gi] = v1; S2h[gi] = v2;
    }
  }
}

// ---- K2: closed-form NCE from power sums (S1,S2), 128 blocks; deterministic
// last-block finalize (atomic counter, reset by k_sweep) folds final reduce in.
__global__ __launch_bounds__(256) void k_post(const float* __restrict__ S1h,
                                              const float* __restrict__ S2h,
                                              const float* __restrict__ P,
                                              const double* __restrict__ p_ce,
                                              double* __restrict__ p_nce,
                                              unsigned int* __restrict__ counter,
                                              float* __restrict__ out) {
  __shared__ double smr[4];
  __shared__ int isLast;
  const int t = threadIdx.x, b = blockIdx.x;
  const int lane = t & 63, w = t >> 6;
  double nce = 0.0;
  {
    int task = b * 256 + t;  // 0..32767
    int g = task >> 3, j = task & 7, i = g >> 9;
    size_t gi = ((size_t)g * 8 + i) * 2;
    float s1i = S1h[gi] + S1h[gi + 1];
    float s2i = S2h[gi] + S2h[gi + 1];
    float Egg = P[(size_t)g * 8 + i];
    float val;
    if (j != i) {
      size_t gj = ((size_t)g * 8 + j) * 2;
      float s1j = S1h[gj] + S1h[gj + 1];
      float s2j = S2h[gj] + S2h[gj + 1];
      float div = s1i + s1j;
      float inv = 1.f / div;
      float pmt = P[(size_t)g * 8 + j] * inv;
      float Ls = (s1i + s1j) + inv * (0.5f * (s2i + s2j));
      val = __logf(pmt) - __logf(1.f - pmt) - inv * Ls;
    } else {
      float div = 2.f * s1i + Egg;
      float inv = 1.f / div;
      float pmt = Egg * inv;
      float Ls = s1i + inv * (0.5f * s2i);
      val = 2.f * __logf(pmt) - 4.f * inv * Ls;
    }
    nce = (double)val;
  }
#pragma unroll
  for (int o2 = 32; o2; o2 >>= 1) nce += __shfl_xor(nce, o2);
  if (lane == 0) smr[w] = nce;
  __syncthreads();
  if (t == 0) {
    p_nce[b] = smr[0] + smr[1] + smr[2] + smr[3];
    __threadfence();
    unsigned int old = atomicAdd(counter, 1u);
    isLast = (old == 127u) ? 1 : 0;
  }
  __syncthreads();
  if (isLast) {
    __threadfence();
    double tn = (t < 128) ? p_nce[t] : 0.0;
    double tc = 0.0;
#pragma unroll
    for (int k = 0; k < 16; ++k) tc += p_ce[t + 256 * k];
#pragma unroll
    for (int o2 = 32; o2; o2 >>= 1) {
      tn += __shfl_xor(tn, o2);
      tc += __shfl_xor(tc, o2);
    }
    __shared__ double smn2[4], smc2[4];
    if (lane == 0) { smn2[w] = tn; smc2[w] = tc; }
    __syncthreads();
    if (t == 0) {
      double fn = smn2[0] + smn2[1] + smn2[2] + smn2[3];
      double fc = smc2[0] + smc2[1] + smc2[2] + smc2[3];
      out[0] = ALPHA_ * (-(float)(fn / 1024.0)) + (float)(fc / 4096.0);
    }
  }
}

__global__ void k_sentinel(float* out) {
  if (threadIdx.x == 0) out[0] = 12345.0f;
}

extern "C" void kernel_launch(void* const* d_in, const int* in_sizes, int n_in,
                              void* d_out, int out_size, void* d_ws, size_t ws_size,
                              hipStream_t stream) {
  const float* predicts = (const float*)d_in[0];
  const int* labels = (const int*)d_in[1];
  const float* features = (const float*)d_in[2];

  char* ws = (char*)d_ws;
  const size_t offS1 = 0;                    // 4096*8*2*4 = 256 KiB
  const size_t offS2 = offS1 + 262144;       // 256 KiB
  const size_t offP = offS2 + 262144;        // 128 KiB
  const size_t offCe = offP + 131072;        // 4096 doubles = 32 KiB
  const size_t offNce = offCe + 32768;       // 128 doubles
  const size_t offCnt = offNce + 1024;       // 1 uint
  const size_t need = offCnt + 64;

  float* out = (float*)d_out;
  if (ws_size < need) {
    k_sentinel<<<1, 64, 0, stream>>>(out);
    return;
  }

  float* S1h = (float*)(ws + offS1);
  float* S2h = (float*)(ws + offS2);
  float* P = (float*)(ws + offP);
  double* p_ce = (double*)(ws + offCe);
  double* p_nce = (double*)(ws + offNce);
  unsigned int* counter = (unsigned int*)(ws + offCnt);

  k_sweep<<<1024, 256, 0, stream>>>(features, predicts, labels, S1h, S2h, P,
                                    p_ce, counter);
  k_post<<<128, 256, 0, stream>>>(S1h, S2h, P, p_ce, p_nce, counter, out);
}